// Round 10
// baseline (1206.676 us; speedup 1.0000x reference)
//
#include <hip/hip_runtime.h>
#include <math.h>

// Problem constants (from reference setup_inputs)
constexpr int NUc = 100000;   // users
constexpr int NIc = 50000;    // items
constexpr int Ec  = 800000;   // edges
constexpr int Bc  = 1024;     // batch
// D = 64 everywhere

typedef __attribute__((ext_vector_type(8))) short short8;            // 8 bf16 = 4 VGPR (MFMA A/B)
typedef __attribute__((ext_vector_type(8))) unsigned short ushort8;  // 8 bf16 payload
typedef __attribute__((ext_vector_type(4))) unsigned short ushort4v; // 8 B chunk
typedef __attribute__((ext_vector_type(4))) float floatx4;           // MFMA C/D

__device__ __forceinline__ float sigf(float x) { return 1.f / (1.f + __expf(-x)); }
__device__ __forceinline__ float maskf(float u) { return (u > 0.25f) ? (1.f / 0.75f) : 0.f; }
__device__ __forceinline__ unsigned short f2bf(float f) {   // RNE fp32->bf16
    unsigned int u = __float_as_uint(f);
    unsigned int r = (u + 0x7fffu + ((u >> 16) & 1u)) >> 16;
    return (unsigned short)r;
}
__device__ __forceinline__ float bf2f(unsigned short u) {
    return __uint_as_float((unsigned int)u << 16);
}

// ---------------- CSR build (fused u+i) ----------------
__global__ void hist_both(const int* __restrict__ esrc, const int* __restrict__ edst,
                          int* __restrict__ cntAll, int n) {
    int i = blockIdx.x * blockDim.x + threadIdx.x;
    if (i < n) {
        atomicAdd(&cntAll[esrc[i]], 1);
        atomicAdd(&cntAll[NUc + edst[i]], 1);
    }
}

__global__ void scan_block(const int* __restrict__ cnt, int* __restrict__ scanAll,
                           int* __restrict__ bsum, int N) {
    __shared__ int sh[1024];
    int i = blockIdx.x * 1024 + threadIdx.x;
    int v = (i < N) ? cnt[i] : 0;
    sh[threadIdx.x] = v;
    __syncthreads();
    for (int off = 1; off < 1024; off <<= 1) {
        int t = (threadIdx.x >= off) ? sh[threadIdx.x - off] : 0;
        __syncthreads();
        sh[threadIdx.x] += t;
        __syncthreads();
    }
    if (i < N) scanAll[i] = sh[threadIdx.x];          // inclusive within chunk
    if (threadIdx.x == 1023) bsum[blockIdx.x] = sh[1023];
}

__global__ void scan_bsums(int* __restrict__ bsum, int nb) {  // nb <= 256
    __shared__ int sh[256];
    int t = threadIdx.x;
    int v = (t < nb) ? bsum[t] : 0;
    sh[t] = v;
    __syncthreads();
    for (int off = 1; off < 256; off <<= 1) {
        int x = (t >= off) ? sh[t - off] : 0;
        __syncthreads();
        sh[t] += x;
        __syncthreads();
    }
    if (t < nb) bsum[t] = sh[t] - v;                  // exclusive
}

// writes rpu/rpi (prefix arrays) and curu/curi (running cursors = exclusive prefix)
__global__ void scan_add_cur(const int* __restrict__ scanAll, const int* __restrict__ bsum,
                             const int* __restrict__ cnt,
                             int* __restrict__ rpu, int* __restrict__ rpi,
                             int* __restrict__ curu, int* __restrict__ curi) {
    int i = blockIdx.x * blockDim.x + threadIdx.x;
    if (i >= NUc + NIc) return;
    int v = scanAll[i] + bsum[i >> 10];               // global inclusive scan
    if (i < NUc) {
        rpu[i + 1] = v;
        if (i == 0) rpu[0] = 0;
        curu[i] = v - cnt[i];
    } else {
        int j = i - NUc;
        rpi[j + 1] = v - Ec;                          // item scan starts after E user entries
        if (j == 0) rpi[0] = 0;
        curi[j] = v - Ec - cnt[i];
    }
}

// Only the irreducible scatters (perm inverse maps); col arrays built later by gather.
__global__ void fill_both(const int* __restrict__ esrc, const int* __restrict__ edst,
                          int* __restrict__ curu, int* __restrict__ curi,
                          int* __restrict__ posu, int* __restrict__ permu,
                          int* __restrict__ permi, int n) {
    int i = blockIdx.x * blockDim.x + threadIdx.x;
    if (i >= n) return;
    int s = esrc[i], d = edst[i];
    int pu = atomicAdd(&curu[s], 1);
    posu[i] = pu;          // sequential
    permu[pu] = i;         // scatter (irreducible)
    int pi = atomicAdd(&curi[d], 1);
    permi[pi] = i;         // scatter (irreducible)
}

__global__ void build_rowu(const int* __restrict__ rp, int* __restrict__ rowu, int N) {
    int r = blockIdx.x * blockDim.x + threadIdx.x;
    if (r < N) {
        int s = rp[r], e = rp[r + 1];
        for (int p = s; p < e; ++p) rowu[p] = r;
    }
}

// p-order gather build: col arrays + main weights + adjacency, both directions.
// All writes sequential; gathers hit L2-resident e-order arrays.
__global__ void build_w_main_both(const int* __restrict__ permu, const int* __restrict__ permi,
                                  const int* __restrict__ esrc, const int* __restrict__ edst,
                                  const float* __restrict__ adj, const float* __restrict__ dmain,
                                  int* __restrict__ colu, int* __restrict__ coli,
                                  float* __restrict__ wMu0, float* __restrict__ wMu1,
                                  float* __restrict__ adjPu,
                                  float* __restrict__ wMi0, float* __restrict__ wMi1,
                                  float* __restrict__ adjPi) {
    int p = blockIdx.x * blockDim.x + threadIdx.x;
    if (p < Ec) {
        int e = permu[p];
        float a = adj[e];
        colu[p] = edst[e];
        wMu0[p] = a * maskf(dmain[e]);
        wMu1[p] = a * maskf(dmain[2 * (size_t)Ec + e]);
        adjPu[p] = a;
    } else if (p < 2 * Ec) {
        p -= Ec;
        int e = permi[p];
        float a = adj[e];
        coli[p] = esrc[e];
        wMi0[p] = a * maskf(dmain[(size_t)Ec + e]);
        wMi1[p] = a * maskf(dmain[3 * (size_t)Ec + e]);
        adjPi[p] = a;
    }
}

// p-order gather build: augmented weights, both directions
__global__ void build_w_aug_both(const int* __restrict__ permu, const int* __restrict__ permi,
                                 const float* __restrict__ av, const float* __restrict__ daug,
                                 float* __restrict__ wAu0, float* __restrict__ wAu1,
                                 float* __restrict__ wAi0, float* __restrict__ wAi1) {
    int p = blockIdx.x * blockDim.x + threadIdx.x;
    if (p < Ec) {
        int e = permu[p];
        float a = av[e];
        wAu0[p] = a * maskf(daug[e]);
        wAu1[p] = a * maskf(daug[2 * (size_t)Ec + e]);
    } else if (p < 2 * Ec) {
        p -= Ec;
        int e = permi[p];
        float a = av[e];
        wAi0[p] = a * maskf(daug[(size_t)Ec + e]);
        wAi1[p] = a * maskf(daug[3 * (size_t)Ec + e]);
    }
}

// ---------------- pull SpMM core (bf16 gather, fp32 accumulate) ----------------
__device__ __forceinline__ void spmm_core(
        const int* __restrict__ rp, const int* __restrict__ col,
        const float* __restrict__ w, const unsigned short* __restrict__ Xbf,
        float* __restrict__ Acc, const float* __restrict__ Base,
        unsigned short* __restrict__ Ybf, unsigned short* __restrict__ Accbf,
        int row, int lane) {
    int s = rp[row], e = rp[row + 1];
    float acc = 0.f;
    int j = s;
    for (; j + 4 <= e; j += 4) {
        int c0 = col[j], c1 = col[j + 1], c2 = col[j + 2], c3 = col[j + 3];
        float w0 = w[j], w1 = w[j + 1], w2 = w[j + 2], w3 = w[j + 3];
        float x0 = bf2f(Xbf[(size_t)c0 * 64 + lane]);
        float x1 = bf2f(Xbf[(size_t)c1 * 64 + lane]);
        float x2 = bf2f(Xbf[(size_t)c2 * 64 + lane]);
        float x3 = bf2f(Xbf[(size_t)c3 * 64 + lane]);
        acc = fmaf(w0, x0, acc);
        acc = fmaf(w1, x1, acc);
        acc = fmaf(w2, x2, acc);
        acc = fmaf(w3, x3, acc);
    }
    for (; j < e; ++j) acc = fmaf(w[j], bf2f(Xbf[(size_t)col[j] * 64 + lane]), acc);
    size_t o = (size_t)row * 64 + lane;
    if (Acc) {
        float nv = (Base ? Base[o] : Acc[o]) + acc;
        Acc[o] = nv;
        if (Accbf) Accbf[o] = f2bf(nv);
    }
    if (Ybf) Ybf[o] = f2bf(acc);
}

// fused u-side + i-side SpMM (blockIdx split)
__global__ void spmm_bf2(int blocksA,
        const int* __restrict__ rpA, const int* __restrict__ colA, const float* __restrict__ wA,
        const unsigned short* __restrict__ XA, float* __restrict__ AccA,
        const float* __restrict__ BaseA, unsigned short* __restrict__ YA,
        unsigned short* __restrict__ AbfA, int NA,
        const int* __restrict__ rpB, const int* __restrict__ colB, const float* __restrict__ wB,
        const unsigned short* __restrict__ XB, float* __restrict__ AccB,
        const float* __restrict__ BaseB, unsigned short* __restrict__ YB,
        unsigned short* __restrict__ AbfB, int NB) {
    int lane = threadIdx.x & 63;
    int w4 = threadIdx.x >> 6;
    int bx = blockIdx.x;
    if (bx < blocksA) {
        int row = bx * 4 + w4;
        if (row < NA) spmm_core(rpA, colA, wA, XA, AccA, BaseA, YA, AbfA, row, lane);
    } else {
        int row = (bx - blocksA) * 4 + w4;
        if (row < NB) spmm_core(rpB, colB, wB, XB, AccB, BaseB, YB, AbfB, row, lane);
    }
}

// ---------------- prep_both: MFMA GEMVs + packs + att dots ----------------
constexpr int WT = 68;
__global__ void __launch_bounds__(256) prep_both(
        const unsigned short* __restrict__ Eu0bf, const unsigned short* __restrict__ hubf,
        const unsigned short* __restrict__ Subf,
        const unsigned short* __restrict__ Ei0bf, const unsigned short* __restrict__ hibf,
        const unsigned short* __restrict__ Sibf,
        const float* __restrict__ W1u, const float* __restrict__ Wg,
        const float* __restrict__ W1i, const float* __restrict__ att,
        unsigned short* __restrict__ PU, unsigned short* __restrict__ PI,
        float* __restrict__ auv, float* __restrict__ aiv, int blocksU) {
    __shared__ unsigned short WtA[64 * WT];
    __shared__ unsigned short WtB[64 * WT];
    bool uside = (int)blockIdx.x < blocksU;
    const float* Wa = uside ? W1u : W1i;
    for (int t = threadIdx.x; t < 4096; t += 256) {
        int n = t >> 6, k = t & 63;
        WtA[n * WT + k] = f2bf(Wa[k * 64 + n]);
        if (uside) WtB[n * WT + k] = f2bf(Wg[k * 64 + n]);
    }
    __syncthreads();

    int lane = threadIdx.x & 63;
    int m = lane & 15, quad = lane >> 4;
    int wv = threadIdx.x >> 6;

    int tile, ntiles;
    const unsigned short* X;
    unsigned short* P;
    const float* attp;
    float* aout;
    if (uside) {
        tile = blockIdx.x * 4 + wv; ntiles = NUc / 16;
        X = Eu0bf; P = PU; attp = att; aout = auv;
    } else {
        tile = (blockIdx.x - blocksU) * 4 + wv; ntiles = NIc / 16;
        X = Ei0bf; P = PI; attp = att + 64; aout = aiv;
    }
    if (tile >= ntiles) return;
    int row0 = tile * 16;

    short8 bA[4][2], bB[4][2];
#pragma unroll
    for (int tt = 0; tt < 4; ++tt) {
#pragma unroll
        for (int kf = 0; kf < 2; ++kf) {
            bA[tt][kf] = *(const short8*)(WtA + (tt * 16 + m) * WT + kf * 32 + quad * 8);
            if (uside) bB[tt][kf] = *(const short8*)(WtB + (tt * 16 + m) * WT + kf * 32 + quad * 8);
        }
    }
    const short8* ap = (const short8*)(X + (size_t)(row0 + m) * 64 + quad * 8);
    short8 a0 = ap[0], a1 = ap[4];

#pragma unroll
    for (int tt = 0; tt < 4; ++tt) {
        floatx4 c = (floatx4){0.f, 0.f, 0.f, 0.f};
        c = __builtin_amdgcn_mfma_f32_16x16x32_bf16(a0, bA[tt][0], c, 0, 0, 0);
        c = __builtin_amdgcn_mfma_f32_16x16x32_bf16(a1, bA[tt][1], c, 0, 0, 0);
#pragma unroll
        for (int r = 0; r < 4; ++r)
            P[(size_t)(row0 + quad * 4 + r) * 192 + tt * 16 + m] = f2bf(c[r]);
    }
    if (uside) {
        const short8* hp = (const short8*)(hubf + (size_t)(row0 + m) * 64 + quad * 8);
        short8 h0 = hp[0], h1 = hp[4];
#pragma unroll
        for (int tt = 0; tt < 4; ++tt) {
            floatx4 c = (floatx4){0.f, 0.f, 0.f, 0.f};
            c = __builtin_amdgcn_mfma_f32_16x16x32_bf16(h0, bB[tt][0], c, 0, 0, 0);
            c = __builtin_amdgcn_mfma_f32_16x16x32_bf16(h1, bB[tt][1], c, 0, 0, 0);
#pragma unroll
            for (int r = 0; r < 4; ++r)
                P[(size_t)(row0 + quad * 4 + r) * 192 + 64 + tt * 16 + m] = f2bf(c[r]);
        }
    } else {
#pragma unroll
        for (int t = 0; t < 2; ++t) {
            int c = lane * 2 + t;
            int row = c >> 3, o8 = (c & 7) * 8;
            *(ushort8*)(P + (size_t)(row0 + row) * 192 + 64 + o8) =
                *(const ushort8*)(hibf + (size_t)(row0 + row) * 64 + o8);
        }
    }
    const unsigned short* Sb = uside ? Subf : Sibf;
#pragma unroll
    for (int t = 0; t < 2; ++t) {
        int c = lane * 2 + t;
        int row = c >> 3, o8 = (c & 7) * 8;
        *(ushort8*)(P + (size_t)(row0 + row) * 192 + 128 + o8) =
            *(const ushort8*)(Sb + (size_t)(row0 + row) * 64 + o8);
    }
    {
        const unsigned short* xr = X + (size_t)(row0 + m) * 64 + quad * 16;
        float ad = 0.f;
#pragma unroll
        for (int j = 0; j < 16; ++j) ad = fmaf(bf2f(xr[j]), attp[quad * 16 + j], ad);
        ad += __shfl_xor(ad, 16, 64);
        ad += __shfl_xor(ad, 32, 64);
        if (lane < 16) aout[row0 + lane] = ad;
    }
}

// ---------------- fp32->bf16 conversion, both embedding tables in one launch ----
__global__ void cvt_both(const float4* __restrict__ Xu, ushort4* __restrict__ Yu, int n4u,
                         const float4* __restrict__ Xi, ushort4* __restrict__ Yi, int n4i) {
    int i = blockIdx.x * blockDim.x + threadIdx.x;
    if (i < n4u) {
        float4 v = Xu[i];
        Yu[i] = make_ushort4(f2bf(v.x), f2bf(v.y), f2bf(v.z), f2bf(v.w));
    } else {
        i -= n4u;
        if (i < n4i) {
            float4 v = Xi[i];
            Yi[i] = make_ushort4(f2bf(v.x), f2bf(v.y), f2bf(v.z), f2bf(v.w));
        }
    }
}

// ---------------- edge pass 1 (CSR-u order, LDS-staged item rows) ----------------
__global__ void __launch_bounds__(128) edge_pass1(
        const int* __restrict__ rowu, const int* __restrict__ colP,
        const unsigned short* __restrict__ PU, const unsigned short* __restrict__ PI,
        const float* __restrict__ b1, const float* __restrict__ W2,
        const float* __restrict__ b2,
        const float* __restrict__ auv, const float* __restrict__ aiv,
        float4* __restrict__ vp4, int E) {
    __shared__ ushort4v lds4[128 * 49];   // 392 B/row
    int p0 = blockIdx.x * 128;
    int tid = threadIdx.x;
#pragma unroll
    for (int it = 0; it < 24; ++it) {
        int flat = it * 128 + tid;
        int row = flat / 24, c = flat - row * 24;
        int d = colP[p0 + row];
        ushort8 g = *(const ushort8*)(PI + (size_t)d * 192 + c * 8);
        ushort4v lo = {g[0], g[1], g[2], g[3]};
        ushort4v hi = {g[4], g[5], g[6], g[7]};
        lds4[row * 49 + c * 2]     = lo;
        lds4[row * 49 + c * 2 + 1] = hi;
    }
    __syncthreads();
    int p = p0 + tid;
    int s = rowu[p];
    int d = colP[p];
    const ushort8* pu = (const ushort8*)(PU + (size_t)s * 192);
    const ushort4v* pl = lds4 + tid * 49;
    float r1 = 0.f, r2 = 0.f, r3 = 0.f;
#pragma unroll
    for (int k = 0; k < 8; ++k) {
        ushort8 u1 = pu[k], hu = pu[8 + k], su = pu[16 + k];
        ushort4v i1a = pl[2 * k], i1b = pl[2 * k + 1];
        ushort4v hia = pl[16 + 2 * k], hib = pl[16 + 2 * k + 1];
        ushort4v sia = pl[32 + 2 * k], sib = pl[32 + 2 * k + 1];
#pragma unroll
        for (int j = 0; j < 4; ++j) {
            float h = bf2f(u1[j]) + bf2f(i1a[j]) + b1[k * 8 + j];
            r1 = fmaf(fmaxf(h, 0.f), W2[k * 8 + j], r1);
            r2 = fmaf(bf2f(hu[j]), bf2f(hia[j]), r2);
            r3 = fmaf(bf2f(su[j]), bf2f(sia[j]), r3);
        }
#pragma unroll
        for (int j = 0; j < 4; ++j) {
            float h = bf2f(u1[4 + j]) + bf2f(i1b[j]) + b1[k * 8 + 4 + j];
            r1 = fmaf(fmaxf(h, 0.f), W2[k * 8 + 4 + j], r1);
            r2 = fmaf(bf2f(hu[4 + j]), bf2f(hib[j]), r2);
            r3 = fmaf(bf2f(su[4 + j]), bf2f(sib[j]), r3);
        }
    }
    float v0 = sigf(r1 + b2[0]);                   // MLP view
    float v2 = sigf(r2);                           // GCN view
    float ax = auv[s] + aiv[d];
    float v3 = sigf(ax > 0.f ? ax : 0.2f * ax);    // ATT view (leaky 0.2)
    float pre = sigf(r3);
    vp4[p] = make_float4(v0, v2, v3, pre);
}

// ---------------- pass 2a (e-order): gather vp4, views + softmax-exp sums ----
__global__ void edge_pass2a(const float4* __restrict__ vp4, const int* __restrict__ posu,
                            const float* __restrict__ fw, const float* __restrict__ fb,
                            const float* __restrict__ wv,
                            float4* __restrict__ viewsE, float* __restrict__ preE,
                            float* __restrict__ sumexp, int E) {
    int e = blockIdx.x * blockDim.x + threadIdx.x;
    float ex0 = 0.f, ex1 = 0.f, ex2 = 0.f, ex3 = 0.f;
    if (e < E) {
        float4 t = vp4[posu[e]];
        float v0 = t.x, v2 = t.y, v3 = t.z;
        float v1 = sigf(wv[e]);
        viewsE[e] = make_float4(v0, v1, v2, v3);
        preE[e] = t.w;
        float fwe = fw[e], fbe = fb[e];
        ex0 = __expf(tanhf(fmaf(fwe, v0, fbe)));
        ex1 = __expf(tanhf(fmaf(fwe, v1, fbe)));
        ex2 = __expf(tanhf(fmaf(fwe, v2, fbe)));
        ex3 = __expf(tanhf(fmaf(fwe, v3, fbe)));
    }
#pragma unroll
    for (int off = 32; off; off >>= 1) {
        ex0 += __shfl_xor(ex0, off, 64);
        ex1 += __shfl_xor(ex1, off, 64);
        ex2 += __shfl_xor(ex2, off, 64);
        ex3 += __shfl_xor(ex3, off, 64);
    }
    __shared__ float sh[4][4];
    int w = threadIdx.x >> 6;
    if ((threadIdx.x & 63) == 0) {
        sh[w][0] = ex0; sh[w][1] = ex1; sh[w][2] = ex2; sh[w][3] = ex3;
    }
    __syncthreads();
    if (threadIdx.x < 4)
        atomicAdd(&sumexp[threadIdx.x],
                  sh[0][threadIdx.x] + sh[1][threadIdx.x] + sh[2][threadIdx.x] + sh[3][threadIdx.x]);
}

// ---------------- pass 2b (e-order, sequential writes): av[e] = baew*adj ----
__global__ void edge_pass2b(const float4* __restrict__ viewsE, const float* __restrict__ preE,
                            const float* __restrict__ fw, const float* __restrict__ fb,
                            const float* __restrict__ adj, const float* __restrict__ sumexp,
                            float* __restrict__ av, float* __restrict__ neglog, int E) {
    int e = blockIdx.x * blockDim.x + threadIdx.x;
    float nl = 0.f;
    if (e < E) {
        float s0 = sumexp[0], s1 = sumexp[1], s2 = sumexp[2], s3 = sumexp[3];
        float4 v = viewsE[e];
        float fwe = fw[e], fbe = fb[e];
        float w0 = __expf(tanhf(fmaf(fwe, v.x, fbe))) / s0;
        float w1 = __expf(tanhf(fmaf(fwe, v.y, fbe))) / s1;
        float w2 = __expf(tanhf(fmaf(fwe, v.z, fbe))) / s2;
        float w3 = __expf(tanhf(fmaf(fwe, v.w, fbe))) / s3;
        float agw = w0 * v.x + w1 * v.y + w2 * v.z + w3 * v.w;
        float sv = v.x + v.y + v.z + v.w;
        float Ag = (sv - 3.f * agw) * 0.2f;            // (sum(views)-3*Ag)/5
        float bw = preE[e] * Ag;
        av[e] = bw * adj[e];
        nl = -logf(bw);
    }
#pragma unroll
    for (int off = 32; off; off >>= 1) nl += __shfl_xor(nl, off, 64);
    __shared__ float sh4[4];
    if ((threadIdx.x & 63) == 0) sh4[threadIdx.x >> 6] = nl;
    __syncthreads();
    if (threadIdx.x == 0) atomicAdd(neglog, sh4[0] + sh4[1] + sh4[2] + sh4[3]);
}

// ---------------- gather+cvt batch rows, both sides ----------------
__global__ void gather_cvt_both(const float* __restrict__ Zu, const int* __restrict__ uids,
                                unsigned short* __restrict__ Gu,
                                const float* __restrict__ Zi, const int* __restrict__ iids,
                                unsigned short* __restrict__ Gi) {
    int t = blockIdx.x * blockDim.x + threadIdx.x;
    if (t < Bc * 64) {
        Gu[t] = f2bf(Zu[(size_t)uids[t >> 6] * 64 + (t & 63)]);
    } else {
        t -= Bc * 64;
        if (t < Bc * 64) Gi[t] = f2bf(Zi[(size_t)iids[t >> 6] * 64 + (t & 63)]);
    }
}

// ---------------- contrastive LSE via MFMA (core + fused launch) ----------------
__device__ __forceinline__ void lse_core(const unsigned short* __restrict__ Gbf,
                                         const unsigned short* __restrict__ Ebf,
                                         float* __restrict__ sums, int N, int tilesPerChunk,
                                         int wid, int lane) {
    int bgroup = wid & 15;       // 16 groups x 64 b
    int chunk = wid >> 4;
    int ntiles = N >> 4;
    int t0 = chunk * tilesPerChunk;
    if (t0 >= ntiles) return;
    int t1 = t0 + tilesPerChunk; if (t1 > ntiles) t1 = ntiles;
    int m = lane & 15, quad = lane >> 4;

    short8 a0[4], a1[4];
#pragma unroll
    for (int t = 0; t < 4; ++t) {
        const short8* ap = (const short8*)(Gbf + ((size_t)(bgroup * 64 + t * 16 + m)) * 64 + quad * 8);
        a0[t] = ap[0];
        a1[t] = ap[4];
    }
    floatx4 rs[4];
#pragma unroll
    for (int t = 0; t < 4; ++t) rs[t] = (floatx4){0.f, 0.f, 0.f, 0.f};

    for (int jt = t0; jt < t1; ++jt) {
        const short8* bp = (const short8*)(Ebf + ((size_t)(jt * 16 + m)) * 64 + quad * 8);
        short8 bf0 = bp[0], bf1 = bp[4];
#pragma unroll
        for (int t = 0; t < 4; ++t) {
            floatx4 c = (floatx4){0.f, 0.f, 0.f, 0.f};
            c = __builtin_amdgcn_mfma_f32_16x16x32_bf16(a0[t], bf0, c, 0, 0, 0);
            c = __builtin_amdgcn_mfma_f32_16x16x32_bf16(a1[t], bf1, c, 0, 0, 0);
#pragma unroll
            for (int r = 0; r < 4; ++r) rs[t][r] += __expf(c[r] * 5.f);
        }
    }
#pragma unroll
    for (int t = 0; t < 4; ++t) {
#pragma unroll
        for (int r = 0; r < 4; ++r) {
            float v = rs[t][r];
            v += __shfl_xor(v, 1, 64);
            v += __shfl_xor(v, 2, 64);
            v += __shfl_xor(v, 4, 64);
            v += __shfl_xor(v, 8, 64);
            if (m == 0) atomicAdd(&sums[bgroup * 64 + t * 16 + quad * 4 + r], v);
        }
    }
}

__global__ void lse_both(const unsigned short* __restrict__ Gu, const unsigned short* __restrict__ Su,
                         float* __restrict__ sums_u,
                         const unsigned short* __restrict__ Gi, const unsigned short* __restrict__ Si,
                         float* __restrict__ sums_i) {
    int lane = threadIdx.x & 63;
    int w4 = threadIdx.x >> 6;
    if ((int)blockIdx.x < 640) {
        lse_core(Gu, Su, sums_u, NUc, 40, blockIdx.x * 4 + w4, lane);
    } else {
        lse_core(Gi, Si, sums_i, NIc, 40, (blockIdx.x - 640) * 4 + w4, lane);
    }
}

// ---------------- batch partials: wave per b, coalesced row loads ----------------
__global__ void batch_partial(const float* __restrict__ Su, const float* __restrict__ Si,
                              const float* __restrict__ Zu, const float* __restrict__ Zi,
                              const int* __restrict__ uids, const int* __restrict__ iids,
                              const int* __restrict__ pids, const int* __restrict__ nids,
                              float* __restrict__ pos_b, float* __restrict__ bpr_b) {
    int b = blockIdx.x * (blockDim.x >> 6) + (threadIdx.x >> 6);
    if (b >= Bc) return;
    int lane = threadIdx.x & 63;
    int u = uids[b], ii = iids[b], p = pids[b], n = nids[b];
    float zu = Zu[(size_t)u * 64 + lane],  su = Su[(size_t)u * 64 + lane];
    float zi = Zi[(size_t)ii * 64 + lane], si = Si[(size_t)ii * 64 + lane];
    float pe = Si[(size_t)p * 64 + lane],  ne = Si[(size_t)n * 64 + lane];
    float du = zu * su, di = zi * si, dp = su * pe, dn = su * ne;
#pragma unroll
    for (int off = 32; off; off >>= 1) {
        du += __shfl_xor(du, off, 64);
        di += __shfl_xor(di, off, 64);
        dp += __shfl_xor(dp, off, 64);
        dn += __shfl_xor(dn, off, 64);
    }
    if (lane == 0) {
        pos_b[b] = fminf(fmaxf(du * 5.f, -5.f), 5.f) + fminf(fmaxf(di * 5.f, -5.f), 5.f);
        bpr_b[b] = log1pf(__expf(-(dp - dn)));         // -log(sigmoid(diff))
    }
}

// ---------------- all 12 L2-reg sums in one kernel ----------------
__global__ void sumsq_all(const float* __restrict__ p0, const float* __restrict__ p1,
                          const float* __restrict__ p2, const float* __restrict__ p3,
                          const float* __restrict__ p4, const float* __restrict__ p5,
                          const float* __restrict__ p6, const float* __restrict__ p7,
                          const float* __restrict__ p8, const float* __restrict__ p9,
                          const float* __restrict__ p10, const float* __restrict__ p11,
                          float* __restrict__ acc) {
    const int TOT = 6400000 + 3200000 + 3 * 800000 + 3 * 4096 + 128 + 64 + 64 + 1;
    float s = 0.f;
    for (int t = blockIdx.x * blockDim.x + threadIdx.x; t < TOT; t += gridDim.x * blockDim.x) {
        int i = t;
        const float* P;
        if (i < 6400000) P = p0;
        else if ((i -= 6400000) < 3200000) P = p1;
        else if ((i -= 3200000) < 800000) P = p2;
        else if ((i -= 800000) < 800000) P = p3;
        else if ((i -= 800000) < 800000) P = p4;
        else if ((i -= 800000) < 4096) P = p5;
        else if ((i -= 4096) < 4096) P = p6;
        else if ((i -= 4096) < 4096) P = p7;
        else if ((i -= 4096) < 128) P = p8;
        else if ((i -= 128) < 64) P = p9;
        else if ((i -= 64) < 64) P = p10;
        else { i -= 64; P = p11; }
        float v = P[i];
        s = fmaf(v, v, s);
    }
#pragma unroll
    for (int off = 32; off; off >>= 1) s += __shfl_xor(s, off, 64);
    __shared__ float sh[4];
    if ((threadIdx.x & 63) == 0) sh[threadIdx.x >> 6] = s;
    __syncthreads();
    if (threadIdx.x == 0) atomicAdd(acc, sh[0] + sh[1] + sh[2] + sh[3]);
}

// ---------------- final combine (tiny) ----------------
__global__ void finalize_kernel(const float* __restrict__ sumexp_u, const float* __restrict__ sumexp_i,
                                const float* __restrict__ pos_b, const float* __restrict__ bpr_b,
                                const float* __restrict__ neglog, const float* __restrict__ regsum,
                                float* __restrict__ out) {
    int b = threadIdx.x;  // 1024
    float lse = logf(sumexp_u[b] + 1e-8f) + logf(sumexp_i[b] + 1e-8f);
    float pos = pos_b[b];
    float bpr = bpr_b[b];
#pragma unroll
    for (int off = 32; off; off >>= 1) {
        lse += __shfl_xor(lse, off, 64);
        pos += __shfl_xor(pos, off, 64);
        bpr += __shfl_xor(bpr, off, 64);
    }
    __shared__ float sl[16], sp[16], sb[16];
    int w = b >> 6;
    if ((b & 63) == 0) { sl[w] = lse; sp[w] = pos; sb[w] = bpr; }
    __syncthreads();
    if (b == 0) {
        float L = 0.f, P = 0.f, Bz = 0.f;
        for (int i = 0; i < 16; ++i) { L += sl[i]; P += sp[i]; Bz += sb[i]; }
        float neg_sc = L * (1.f / Bc);
        float pos_sc = P * (1.f / Bc);
        float loss_cl = neg_sc - pos_sc;
        float l1cl = 0.2f * loss_cl;
        float loss_bpr = Bz * (1.f / Bc);
        float loss_pr = 0.01f * (neglog[0] * (1.f / Ec));
        float loss_reg = 1e-5f * regsum[0];
        out[0] = loss_bpr + l1cl + loss_pr + loss_reg;
        out[1] = loss_bpr;
        out[2] = l1cl;
        out[3] = loss_pr;
    }
}

extern "C" void kernel_launch(void* const* d_in, const int* in_sizes, int n_in,
                              void* d_out, int out_size, void* d_ws, size_t ws_size,
                              hipStream_t stream) {
    const float* Eu0    = (const float*)d_in[0];
    const float* Ei0    = (const float*)d_in[1];
    const float* fuse_w = (const float*)d_in[2];
    const float* fuse_b = (const float*)d_in[3];
    const float* W1u    = (const float*)d_in[4];
    const float* W1i    = (const float*)d_in[5];
    const float* b1     = (const float*)d_in[6];
    const float* W2     = (const float*)d_in[7];
    const float* b2     = (const float*)d_in[8];
    const float* att    = (const float*)d_in[9];
    const float* wv     = (const float*)d_in[10];
    const float* Wg     = (const float*)d_in[11];
    const float* adj    = (const float*)d_in[12];
    const float* dmain  = (const float*)d_in[13];
    const float* daug   = (const float*)d_in[14];
    const int*   esrc   = (const int*)d_in[15];
    const int*   edst   = (const int*)d_in[16];
    const int*   uids   = (const int*)d_in[17];
    const int*   iids   = (const int*)d_in[18];
    const int*   pids   = (const int*)d_in[19];
    const int*   nids   = (const int*)d_in[20];
    float* out = (float*)d_out;

    // ---- workspace layout (~224 MB; proven safe) ----
    char* base = (char*)d_ws;
    size_t off = 0;
    auto alloc = [&](size_t bytes) -> char* {
        char* pp = base + off;
        off = (off + bytes + 255) & ~(size_t)255;
        return pp;
    };
    float* Su   = (float*)alloc((size_t)NUc * 64 * 4);
    float* Si   = (float*)alloc((size_t)NIc * 64 * 4);
    // blkZ (38.4 MB): PU [prep..pass1] -> viewsE/preE [pass2a..pass2b] -> Zu/Zi [prop2..finalize]
    char* blkZ = alloc((size_t)NUc * 64 * 4 + (size_t)NIc * 64 * 4);
    unsigned short* PU = (unsigned short*)blkZ;
    float4* viewsE = (float4*)blkZ;
    float* preE   = (float*)(blkZ + (size_t)Ec * 16);
    float* Zu = (float*)blkZ;
    float* Zi = (float*)(blkZ + (size_t)NUc * 64 * 4);
    float4* vp4 = (float4*)alloc((size_t)Ec * 16);
    unsigned short* Eu0bf = (unsigned short*)alloc((size_t)NUc * 64 * 2);
    unsigned short* Ei0bf = (unsigned short*)alloc((size_t)NIc * 64 * 2);
    unsigned short* Subf  = (unsigned short*)alloc((size_t)NUc * 64 * 2);
    unsigned short* Sibf  = (unsigned short*)alloc((size_t)NIc * 64 * 2);
    unsigned short* Bubf  = (unsigned short*)alloc((size_t)NUc * 64 * 2);
    unsigned short* Bibf  = (unsigned short*)alloc((size_t)NIc * 64 * 2);
    unsigned short* hubf  = (unsigned short*)alloc((size_t)NUc * 64 * 2);
    unsigned short* hibf  = (unsigned short*)alloc((size_t)NIc * 64 * 2);
    // blkA (19.2 MB): adjP [build..GCN spmm] -> PI [prep..pass1] -> wA [build_w_aug..prop2]
    char* blkA = alloc((size_t)Ec * 4 * 6);
    float* adjPu = (float*)blkA;
    float* adjPi = (float*)(blkA + (size_t)Ec * 4);
    float* wAu0  = (float*)(blkA + (size_t)Ec * 8);
    float* wAu1  = (float*)(blkA + (size_t)Ec * 12);
    float* wAi0  = (float*)(blkA + (size_t)Ec * 16);
    float* wAi1  = (float*)(blkA + (size_t)Ec * 20);
    unsigned short* PI = (unsigned short*)blkA;
    float* wMu0  = (float*)alloc((size_t)Ec * 4);
    float* wMu1  = (float*)alloc((size_t)Ec * 4);
    float* wMi0  = (float*)alloc((size_t)Ec * 4);
    float* wMi1  = (float*)alloc((size_t)Ec * 4);
    float* av    = (float*)alloc((size_t)Ec * 4);
    float* auv  = (float*)alloc((size_t)NUc * 4);
    float* aiv  = (float*)alloc((size_t)NIc * 4);
    int* rowu  = (int*)alloc((size_t)Ec * 4);
    unsigned short* Gubf = (unsigned short*)alloc((size_t)Bc * 64 * 2);
    unsigned short* Gibf = (unsigned short*)alloc((size_t)Bc * 64 * 2);
    // contiguous scalar-accumulator block (one memset)
    float* scal = (float*)alloc((4 + 1 + 1 + 2 + Bc + Bc) * 4);
    float* sumexp4 = scal;            // 4
    float* neglog  = scal + 4;        // 1
    float* regsum  = scal + 5;        // 1 (+2 pad)
    float* sumexp_u = scal + 8;       // 1024
    float* sumexp_i = scal + 8 + Bc;  // 1024
    float* pos_b = (float*)alloc((size_t)Bc * 4);
    float* bpr_b = (float*)alloc((size_t)Bc * 4);
    int* rpu   = (int*)alloc((size_t)(NUc + 1) * 4);
    int* rpi   = (int*)alloc((size_t)(NIc + 1) * 4);
    int* colu  = (int*)alloc((size_t)Ec * 4);
    int* coli  = (int*)alloc((size_t)Ec * 4);
    int* posu  = (int*)alloc((size_t)Ec * 4);
    int* permu = (int*)alloc((size_t)Ec * 4);
    int* permi = (int*)alloc((size_t)Ec * 4);
    int* cntAll  = (int*)alloc((size_t)(NUc + NIc) * 4);
    int* scanAll = (int*)alloc((size_t)(NUc + NIc) * 4);
    int* curu  = (int*)alloc((size_t)NUc * 4);
    int* curi  = (int*)alloc((size_t)NIc * 4);
    int* bsum  = (int*)alloc(256 * 4);

    dim3 b256(256);
    const int NALL = NUc + NIc;
    const int nbAll = (NALL + 1023) / 1024;   // 147
    const dim3 gE((Ec + 255) / 256);
    const dim3 g2E((2 * Ec + 255) / 256);
    const int blocksU = (NUc + 3) / 4, blocksI = (NIc + 3) / 4;   // 25000 / 12500
    const dim3 gUI(blocksU + blocksI);

    // ---- zero accumulators + counts (2 memsets total) ----
    hipMemsetAsync(cntAll, 0, (size_t)NALL * 4, stream);
    hipMemsetAsync(scal, 0, (4 + 1 + 1 + 2 + Bc + Bc) * 4, stream);

    // ---- CSR build (fused) ----
    hist_both<<<gE, b256, 0, stream>>>(esrc, edst, cntAll, Ec);
    scan_block<<<dim3(nbAll), dim3(1024), 0, stream>>>(cntAll, scanAll, bsum, NALL);
    scan_bsums<<<dim3(1), dim3(256), 0, stream>>>(bsum, nbAll);
    scan_add_cur<<<dim3((NALL + 255) / 256), b256, 0, stream>>>(scanAll, bsum, cntAll,
                                                               rpu, rpi, curu, curi);
    fill_both<<<gE, b256, 0, stream>>>(esrc, edst, curu, curi, posu, permu, permi, Ec);
    build_rowu<<<dim3((NUc + 255) / 256), b256, 0, stream>>>(rpu, rowu, NUc);

    // ---- col arrays + main weights + adjacency in CSR order (gather, sequential writes) ----
    build_w_main_both<<<g2E, b256, 0, stream>>>(permu, permi, esrc, edst, adj, dmain,
                                                colu, coli, wMu0, wMu1, adjPu, wMi0, wMi1, adjPi);

    // ---- bf16 base embeddings (one kernel) ----
    cvt_both<<<dim3(((NUc + NIc) * 16 + 255) / 256), b256, 0, stream>>>(
        (const float4*)Eu0, (ushort4*)Eu0bf, NUc * 16,
        (const float4*)Ei0, (ushort4*)Ei0bf, NIc * 16);

    // ---- propagate 1 (main graph), fused u+i per layer ----
    spmm_bf2<<<gUI, b256, 0, stream>>>(blocksU,
        rpu, colu, wMu0, Ei0bf, Su, Eu0, Bubf, nullptr, NUc,
        rpi, coli, wMi0, Eu0bf, Si, Ei0, Bibf, nullptr, NIc);
    spmm_bf2<<<gUI, b256, 0, stream>>>(blocksU,
        rpu, colu, wMu1, Bibf, Su, nullptr, nullptr, Subf, NUc,     // fused Su->bf16
        rpi, coli, wMi1, Bubf, Si, nullptr, nullptr, Sibf, NIc);    // fused Si->bf16

    // ---- GCN view: h_u = A@Si ; h_i = A.T@Su (fused) ----
    spmm_bf2<<<gUI, b256, 0, stream>>>(blocksU,
        rpu, colu, adjPu, Sibf, nullptr, nullptr, hubf, nullptr, NUc,
        rpi, coli, adjPi, Subf, nullptr, nullptr, hibf, nullptr, NIc);

    // ---- node-feature prep via MFMA (one kernel) ----
    {
        const int tBU = (NUc / 16 + 3) / 4;   // 1563
        const int tBI = (NIc / 16 + 3) / 4;   // 782
        prep_both<<<dim3(tBU + tBI), b256, 0, stream>>>(
            Eu0bf, hubf, Subf, Ei0bf, hibf, Sibf,
            W1u, Wg, W1i, att, PU, PI, auv, aiv, tBU);
    }

    // ---- edge pass 1 (CSR-u order, LDS-staged) ----
    edge_pass1<<<dim3(Ec / 128), dim3(128), 0, stream>>>(
        rowu, colu, PU, PI, b1, W2, b2, auv, aiv, vp4, Ec);

    // ---- pass 2a: views (e-order) + softmax-exp sums (overwrites PU alias) ----
    edge_pass2a<<<gE, b256, 0, stream>>>(vp4, posu, fuse_w, fuse_b, wv,
                                         viewsE, preE, sumexp4, Ec);

    // ---- pass 2b: av[e] sequential + -log(baew) sum ----
    edge_pass2b<<<gE, b256, 0, stream>>>(
        viewsE, preE, fuse_w, fuse_b, adj, sumexp4, av, neglog, Ec);

    // ---- aug weights in CSR order (one kernel; overwrites PI alias) ----
    build_w_aug_both<<<g2E, b256, 0, stream>>>(permu, permi, av, daug, wAu0, wAu1, wAi0, wAi1);

    // ---- propagate 2 (augmented graph), fused u+i (overwrites viewsE alias) ----
    spmm_bf2<<<gUI, b256, 0, stream>>>(blocksU,
        rpu, colu, wAu0, Ei0bf, Zu, Eu0, Bubf, nullptr, NUc,
        rpi, coli, wAi0, Eu0bf, Zi, Ei0, Bibf, nullptr, NIc);
    spmm_bf2<<<gUI, b256, 0, stream>>>(blocksU,
        rpu, colu, wAu1, Bibf, Zu, nullptr, nullptr, nullptr, NUc,
        rpi, coli, wAi1, Bubf, Zi, nullptr, nullptr, nullptr, NIc);

    // ---- contrastive ----
    gather_cvt_both<<<dim3((2 * Bc * 64 + 255) / 256), b256, 0, stream>>>(
        Zu, uids, Gubf, Zi, iids, Gibf);
    lse_both<<<dim3(960), b256, 0, stream>>>(Gubf, Subf, sumexp_u, Gibf, Sibf, sumexp_i);

    // ---- batch partials ----
    batch_partial<<<dim3(Bc / 4), b256, 0, stream>>>(Su, Si, Zu, Zi, uids, iids, pids, nids,
                                                     pos_b, bpr_b);

    // ---- regularization (one kernel) ----
    sumsq_all<<<dim3(4096), b256, 0, stream>>>(Eu0, Ei0, fuse_w, fuse_b, wv,
                                               W1u, W1i, Wg, att, b1, W2, b2, regsum);

    // ---- finalize ----
    finalize_kernel<<<dim3(1), dim3(1024), 0, stream>>>(
        sumexp_u, sumexp_i, pos_b, bpr_b, neglog, regsum, out);
}

// Round 11
// 1158.201 us; speedup vs baseline: 1.0419x; 1.0419x over previous
//
#include <hip/hip_runtime.h>
#include <math.h>

// Problem constants (from reference setup_inputs)
constexpr int NUc = 100000;   // users
constexpr int NIc = 50000;    // items
constexpr int Ec  = 800000;   // edges
constexpr int Bc  = 1024;     // batch
// D = 64 everywhere

typedef __attribute__((ext_vector_type(8))) short short8;            // 8 bf16 = 4 VGPR (MFMA A/B)
typedef __attribute__((ext_vector_type(8))) unsigned short ushort8;  // 8 bf16 payload
typedef __attribute__((ext_vector_type(4))) unsigned short ushort4v; // 8 B chunk
typedef __attribute__((ext_vector_type(4))) float floatx4;           // MFMA C/D

__device__ __forceinline__ float sigf(float x) { return 1.f / (1.f + __expf(-x)); }
__device__ __forceinline__ float maskf(float u) { return (u > 0.25f) ? (1.f / 0.75f) : 0.f; }
__device__ __forceinline__ unsigned short f2bf(float f) {   // RNE fp32->bf16
    unsigned int u = __float_as_uint(f);
    unsigned int r = (u + 0x7fffu + ((u >> 16) & 1u)) >> 16;
    return (unsigned short)r;
}
__device__ __forceinline__ float bf2f(unsigned short u) {
    return __uint_as_float((unsigned int)u << 16);
}

// ---------------- CSR build (fused u+i) ----------------
__global__ void hist_both(const int* __restrict__ esrc, const int* __restrict__ edst,
                          int* __restrict__ cntAll, int n) {
    int i = blockIdx.x * blockDim.x + threadIdx.x;
    if (i < n) {
        atomicAdd(&cntAll[esrc[i]], 1);
        atomicAdd(&cntAll[NUc + edst[i]], 1);
    }
}

__global__ void scan_block(const int* __restrict__ cnt, int* __restrict__ scanAll,
                           int* __restrict__ bsum, int N) {
    __shared__ int sh[1024];
    int i = blockIdx.x * 1024 + threadIdx.x;
    int v = (i < N) ? cnt[i] : 0;
    sh[threadIdx.x] = v;
    __syncthreads();
    for (int off = 1; off < 1024; off <<= 1) {
        int t = (threadIdx.x >= off) ? sh[threadIdx.x - off] : 0;
        __syncthreads();
        sh[threadIdx.x] += t;
        __syncthreads();
    }
    if (i < N) scanAll[i] = sh[threadIdx.x];          // inclusive within chunk
    if (threadIdx.x == 1023) bsum[blockIdx.x] = sh[1023];
}

__global__ void scan_bsums(int* __restrict__ bsum, int nb) {  // nb <= 256
    __shared__ int sh[256];
    int t = threadIdx.x;
    int v = (t < nb) ? bsum[t] : 0;
    sh[t] = v;
    __syncthreads();
    for (int off = 1; off < 256; off <<= 1) {
        int x = (t >= off) ? sh[t - off] : 0;
        __syncthreads();
        sh[t] += x;
        __syncthreads();
    }
    if (t < nb) bsum[t] = sh[t] - v;                  // exclusive
}

// writes rpu/rpi (prefix arrays) and curu/curi (running cursors = exclusive prefix)
__global__ void scan_add_cur(const int* __restrict__ scanAll, const int* __restrict__ bsum,
                             const int* __restrict__ cnt,
                             int* __restrict__ rpu, int* __restrict__ rpi,
                             int* __restrict__ curu, int* __restrict__ curi) {
    int i = blockIdx.x * blockDim.x + threadIdx.x;
    if (i >= NUc + NIc) return;
    int v = scanAll[i] + bsum[i >> 10];               // global inclusive scan
    if (i < NUc) {
        rpu[i + 1] = v;
        if (i == 0) rpu[0] = 0;
        curu[i] = v - cnt[i];
    } else {
        int j = i - NUc;
        rpi[j + 1] = v - Ec;                          // item scan starts after E user entries
        if (j == 0) rpi[0] = 0;
        curi[j] = v - Ec - cnt[i];
    }
}

// 2E threads: one atomic + scatters per thread (halved dependent chain vs R9/R10)
__global__ void fill_both(const int* __restrict__ esrc, const int* __restrict__ edst,
                          int* __restrict__ curu, int* __restrict__ curi,
                          int* __restrict__ colu, int* __restrict__ posu, int* __restrict__ permu,
                          int* __restrict__ coli, int* __restrict__ permi, int n) {
    int t = blockIdx.x * blockDim.x + threadIdx.x;
    if (t < n) {
        int i = t;
        int pu = atomicAdd(&curu[esrc[i]], 1);
        posu[i] = pu;          // sequential
        colu[pu] = edst[i];    // scatter
        permu[pu] = i;         // scatter
    } else if (t < 2 * n) {
        int i = t - n;
        int pi = atomicAdd(&curi[edst[i]], 1);
        coli[pi] = esrc[i];    // scatter
        permi[pi] = i;         // scatter
    }
}

__global__ void build_rowu(const int* __restrict__ rp, int* __restrict__ rowu, int N) {
    int r = blockIdx.x * blockDim.x + threadIdx.x;
    if (r < N) {
        int s = rp[r], e = rp[r + 1];
        for (int p = s; p < e; ++p) rowu[p] = r;
    }
}

// p-order gather build: main weights + adjacency, both directions, one kernel
__global__ void build_w_main_both(const int* __restrict__ permu, const int* __restrict__ permi,
                                  const float* __restrict__ adj, const float* __restrict__ dmain,
                                  float* __restrict__ wMu0, float* __restrict__ wMu1,
                                  float* __restrict__ adjPu,
                                  float* __restrict__ wMi0, float* __restrict__ wMi1,
                                  float* __restrict__ adjPi) {
    int p = blockIdx.x * blockDim.x + threadIdx.x;
    if (p < Ec) {
        int e = permu[p];
        float a = adj[e];
        wMu0[p] = a * maskf(dmain[e]);
        wMu1[p] = a * maskf(dmain[2 * (size_t)Ec + e]);
        adjPu[p] = a;
    } else if (p < 2 * Ec) {
        p -= Ec;
        int e = permi[p];
        float a = adj[e];
        wMi0[p] = a * maskf(dmain[(size_t)Ec + e]);
        wMi1[p] = a * maskf(dmain[3 * (size_t)Ec + e]);
        adjPi[p] = a;
    }
}

// p-order gather build: augmented weights, both directions
__global__ void build_w_aug_both(const int* __restrict__ permu, const int* __restrict__ permi,
                                 const float* __restrict__ av, const float* __restrict__ daug,
                                 float* __restrict__ wAu0, float* __restrict__ wAu1,
                                 float* __restrict__ wAi0, float* __restrict__ wAi1) {
    int p = blockIdx.x * blockDim.x + threadIdx.x;
    if (p < Ec) {
        int e = permu[p];
        float a = av[e];
        wAu0[p] = a * maskf(daug[e]);
        wAu1[p] = a * maskf(daug[2 * (size_t)Ec + e]);
    } else if (p < 2 * Ec) {
        p -= Ec;
        int e = permi[p];
        float a = av[e];
        wAi0[p] = a * maskf(daug[(size_t)Ec + e]);
        wAi1[p] = a * maskf(daug[3 * (size_t)Ec + e]);
    }
}

// ---------------- pull SpMM core (bf16 gather, fp32 accumulate) ----------------
__device__ __forceinline__ void spmm_core(
        const int* __restrict__ rp, const int* __restrict__ col,
        const float* __restrict__ w, const unsigned short* __restrict__ Xbf,
        float* __restrict__ Acc, const float* __restrict__ Base,
        unsigned short* __restrict__ Ybf, unsigned short* __restrict__ Accbf,
        int row, int lane) {
    int s = rp[row], e = rp[row + 1];
    float acc = 0.f;
    int j = s;
    for (; j + 4 <= e; j += 4) {
        int c0 = col[j], c1 = col[j + 1], c2 = col[j + 2], c3 = col[j + 3];
        float w0 = w[j], w1 = w[j + 1], w2 = w[j + 2], w3 = w[j + 3];
        float x0 = bf2f(Xbf[(size_t)c0 * 64 + lane]);
        float x1 = bf2f(Xbf[(size_t)c1 * 64 + lane]);
        float x2 = bf2f(Xbf[(size_t)c2 * 64 + lane]);
        float x3 = bf2f(Xbf[(size_t)c3 * 64 + lane]);
        acc = fmaf(w0, x0, acc);
        acc = fmaf(w1, x1, acc);
        acc = fmaf(w2, x2, acc);
        acc = fmaf(w3, x3, acc);
    }
    for (; j < e; ++j) acc = fmaf(w[j], bf2f(Xbf[(size_t)col[j] * 64 + lane]), acc);
    size_t o = (size_t)row * 64 + lane;
    if (Acc) {
        float nv = (Base ? Base[o] : Acc[o]) + acc;
        Acc[o] = nv;
        if (Accbf) Accbf[o] = f2bf(nv);
    }
    if (Ybf) Ybf[o] = f2bf(acc);
}

// fused u-side + i-side SpMM (blockIdx split)
__global__ void spmm_bf2(int blocksA,
        const int* __restrict__ rpA, const int* __restrict__ colA, const float* __restrict__ wA,
        const unsigned short* __restrict__ XA, float* __restrict__ AccA,
        const float* __restrict__ BaseA, unsigned short* __restrict__ YA,
        unsigned short* __restrict__ AbfA, int NA,
        const int* __restrict__ rpB, const int* __restrict__ colB, const float* __restrict__ wB,
        const unsigned short* __restrict__ XB, float* __restrict__ AccB,
        const float* __restrict__ BaseB, unsigned short* __restrict__ YB,
        unsigned short* __restrict__ AbfB, int NB) {
    int lane = threadIdx.x & 63;
    int w4 = threadIdx.x >> 6;
    int bx = blockIdx.x;
    if (bx < blocksA) {
        int row = bx * 4 + w4;
        if (row < NA) spmm_core(rpA, colA, wA, XA, AccA, BaseA, YA, AbfA, row, lane);
    } else {
        int row = (bx - blocksA) * 4 + w4;
        if (row < NB) spmm_core(rpB, colB, wB, XB, AccB, BaseB, YB, AbfB, row, lane);
    }
}

// ---------------- prep_both: MFMA GEMVs + packs + att dots ----------------
constexpr int WT = 68;
__global__ void __launch_bounds__(256) prep_both(
        const unsigned short* __restrict__ Eu0bf, const unsigned short* __restrict__ hubf,
        const unsigned short* __restrict__ Subf,
        const unsigned short* __restrict__ Ei0bf, const unsigned short* __restrict__ hibf,
        const unsigned short* __restrict__ Sibf,
        const float* __restrict__ W1u, const float* __restrict__ Wg,
        const float* __restrict__ W1i, const float* __restrict__ att,
        unsigned short* __restrict__ PU, unsigned short* __restrict__ PI,
        float* __restrict__ auv, float* __restrict__ aiv, int blocksU) {
    __shared__ unsigned short WtA[64 * WT];
    __shared__ unsigned short WtB[64 * WT];
    bool uside = (int)blockIdx.x < blocksU;
    const float* Wa = uside ? W1u : W1i;
    for (int t = threadIdx.x; t < 4096; t += 256) {
        int n = t >> 6, k = t & 63;
        WtA[n * WT + k] = f2bf(Wa[k * 64 + n]);
        if (uside) WtB[n * WT + k] = f2bf(Wg[k * 64 + n]);
    }
    __syncthreads();

    int lane = threadIdx.x & 63;
    int m = lane & 15, quad = lane >> 4;
    int wv = threadIdx.x >> 6;

    int tile, ntiles;
    const unsigned short* X;
    unsigned short* P;
    const float* attp;
    float* aout;
    if (uside) {
        tile = blockIdx.x * 4 + wv; ntiles = NUc / 16;
        X = Eu0bf; P = PU; attp = att; aout = auv;
    } else {
        tile = (blockIdx.x - blocksU) * 4 + wv; ntiles = NIc / 16;
        X = Ei0bf; P = PI; attp = att + 64; aout = aiv;
    }
    if (tile >= ntiles) return;
    int row0 = tile * 16;

    short8 bA[4][2], bB[4][2];
#pragma unroll
    for (int tt = 0; tt < 4; ++tt) {
#pragma unroll
        for (int kf = 0; kf < 2; ++kf) {
            bA[tt][kf] = *(const short8*)(WtA + (tt * 16 + m) * WT + kf * 32 + quad * 8);
            if (uside) bB[tt][kf] = *(const short8*)(WtB + (tt * 16 + m) * WT + kf * 32 + quad * 8);
        }
    }
    const short8* ap = (const short8*)(X + (size_t)(row0 + m) * 64 + quad * 8);
    short8 a0 = ap[0], a1 = ap[4];

#pragma unroll
    for (int tt = 0; tt < 4; ++tt) {
        floatx4 c = (floatx4){0.f, 0.f, 0.f, 0.f};
        c = __builtin_amdgcn_mfma_f32_16x16x32_bf16(a0, bA[tt][0], c, 0, 0, 0);
        c = __builtin_amdgcn_mfma_f32_16x16x32_bf16(a1, bA[tt][1], c, 0, 0, 0);
#pragma unroll
        for (int r = 0; r < 4; ++r)
            P[(size_t)(row0 + quad * 4 + r) * 192 + tt * 16 + m] = f2bf(c[r]);
    }
    if (uside) {
        const short8* hp = (const short8*)(hubf + (size_t)(row0 + m) * 64 + quad * 8);
        short8 h0 = hp[0], h1 = hp[4];
#pragma unroll
        for (int tt = 0; tt < 4; ++tt) {
            floatx4 c = (floatx4){0.f, 0.f, 0.f, 0.f};
            c = __builtin_amdgcn_mfma_f32_16x16x32_bf16(h0, bB[tt][0], c, 0, 0, 0);
            c = __builtin_amdgcn_mfma_f32_16x16x32_bf16(h1, bB[tt][1], c, 0, 0, 0);
#pragma unroll
            for (int r = 0; r < 4; ++r)
                P[(size_t)(row0 + quad * 4 + r) * 192 + 64 + tt * 16 + m] = f2bf(c[r]);
        }
    } else {
#pragma unroll
        for (int t = 0; t < 2; ++t) {
            int c = lane * 2 + t;
            int row = c >> 3, o8 = (c & 7) * 8;
            *(ushort8*)(P + (size_t)(row0 + row) * 192 + 64 + o8) =
                *(const ushort8*)(hibf + (size_t)(row0 + row) * 64 + o8);
        }
    }
    const unsigned short* Sb = uside ? Subf : Sibf;
#pragma unroll
    for (int t = 0; t < 2; ++t) {
        int c = lane * 2 + t;
        int row = c >> 3, o8 = (c & 7) * 8;
        *(ushort8*)(P + (size_t)(row0 + row) * 192 + 128 + o8) =
            *(const ushort8*)(Sb + (size_t)(row0 + row) * 64 + o8);
    }
    {
        const unsigned short* xr = X + (size_t)(row0 + m) * 64 + quad * 16;
        float ad = 0.f;
#pragma unroll
        for (int j = 0; j < 16; ++j) ad = fmaf(bf2f(xr[j]), attp[quad * 16 + j], ad);
        ad += __shfl_xor(ad, 16, 64);
        ad += __shfl_xor(ad, 32, 64);
        if (lane < 16) aout[row0 + lane] = ad;
    }
}

// ---------------- fp32->bf16 conversion, both embedding tables in one launch ----
__global__ void cvt_both(const float4* __restrict__ Xu, ushort4* __restrict__ Yu, int n4u,
                         const float4* __restrict__ Xi, ushort4* __restrict__ Yi, int n4i) {
    int i = blockIdx.x * blockDim.x + threadIdx.x;
    if (i < n4u) {
        float4 v = Xu[i];
        Yu[i] = make_ushort4(f2bf(v.x), f2bf(v.y), f2bf(v.z), f2bf(v.w));
    } else {
        i -= n4u;
        if (i < n4i) {
            float4 v = Xi[i];
            Yi[i] = make_ushort4(f2bf(v.x), f2bf(v.y), f2bf(v.z), f2bf(v.w));
        }
    }
}

// ---------------- edge pass 1 (CSR-u order, LDS-staged item rows) ----------------
__global__ void __launch_bounds__(128) edge_pass1(
        const int* __restrict__ rowu, const int* __restrict__ colP,
        const unsigned short* __restrict__ PU, const unsigned short* __restrict__ PI,
        const float* __restrict__ b1, const float* __restrict__ W2,
        const float* __restrict__ b2,
        const float* __restrict__ auv, const float* __restrict__ aiv,
        float4* __restrict__ vp4, int E) {
    __shared__ ushort4v lds4[128 * 49];   // 392 B/row
    int p0 = blockIdx.x * 128;
    int tid = threadIdx.x;
#pragma unroll
    for (int it = 0; it < 24; ++it) {
        int flat = it * 128 + tid;
        int row = flat / 24, c = flat - row * 24;
        int d = colP[p0 + row];
        ushort8 g = *(const ushort8*)(PI + (size_t)d * 192 + c * 8);
        ushort4v lo = {g[0], g[1], g[2], g[3]};
        ushort4v hi = {g[4], g[5], g[6], g[7]};
        lds4[row * 49 + c * 2]     = lo;
        lds4[row * 49 + c * 2 + 1] = hi;
    }
    __syncthreads();
    int p = p0 + tid;
    int s = rowu[p];
    int d = colP[p];
    const ushort8* pu = (const ushort8*)(PU + (size_t)s * 192);
    const ushort4v* pl = lds4 + tid * 49;
    float r1 = 0.f, r2 = 0.f, r3 = 0.f;
#pragma unroll
    for (int k = 0; k < 8; ++k) {
        ushort8 u1 = pu[k], hu = pu[8 + k], su = pu[16 + k];
        ushort4v i1a = pl[2 * k], i1b = pl[2 * k + 1];
        ushort4v hia = pl[16 + 2 * k], hib = pl[16 + 2 * k + 1];
        ushort4v sia = pl[32 + 2 * k], sib = pl[32 + 2 * k + 1];
#pragma unroll
        for (int j = 0; j < 4; ++j) {
            float h = bf2f(u1[j]) + bf2f(i1a[j]) + b1[k * 8 + j];
            r1 = fmaf(fmaxf(h, 0.f), W2[k * 8 + j], r1);
            r2 = fmaf(bf2f(hu[j]), bf2f(hia[j]), r2);
            r3 = fmaf(bf2f(su[j]), bf2f(sia[j]), r3);
        }
#pragma unroll
        for (int j = 0; j < 4; ++j) {
            float h = bf2f(u1[4 + j]) + bf2f(i1b[j]) + b1[k * 8 + 4 + j];
            r1 = fmaf(fmaxf(h, 0.f), W2[k * 8 + 4 + j], r1);
            r2 = fmaf(bf2f(hu[4 + j]), bf2f(hib[j]), r2);
            r3 = fmaf(bf2f(su[4 + j]), bf2f(sib[j]), r3);
        }
    }
    float v0 = sigf(r1 + b2[0]);                   // MLP view
    float v2 = sigf(r2);                           // GCN view
    float ax = auv[s] + aiv[d];
    float v3 = sigf(ax > 0.f ? ax : 0.2f * ax);    // ATT view (leaky 0.2)
    float pre = sigf(r3);
    vp4[p] = make_float4(v0, v2, v3, pre);
}

// ---------------- pass 2a (e-order): gather vp4, views + softmax-exp sums ----
__global__ void edge_pass2a(const float4* __restrict__ vp4, const int* __restrict__ posu,
                            const float* __restrict__ fw, const float* __restrict__ fb,
                            const float* __restrict__ wv,
                            float4* __restrict__ viewsE, float* __restrict__ preE,
                            float* __restrict__ sumexp, int E) {
    int e = blockIdx.x * blockDim.x + threadIdx.x;
    float ex0 = 0.f, ex1 = 0.f, ex2 = 0.f, ex3 = 0.f;
    if (e < E) {
        float4 t = vp4[posu[e]];
        float v0 = t.x, v2 = t.y, v3 = t.z;
        float v1 = sigf(wv[e]);
        viewsE[e] = make_float4(v0, v1, v2, v3);
        preE[e] = t.w;
        float fwe = fw[e], fbe = fb[e];
        ex0 = __expf(tanhf(fmaf(fwe, v0, fbe)));
        ex1 = __expf(tanhf(fmaf(fwe, v1, fbe)));
        ex2 = __expf(tanhf(fmaf(fwe, v2, fbe)));
        ex3 = __expf(tanhf(fmaf(fwe, v3, fbe)));
    }
#pragma unroll
    for (int off = 32; off; off >>= 1) {
        ex0 += __shfl_xor(ex0, off, 64);
        ex1 += __shfl_xor(ex1, off, 64);
        ex2 += __shfl_xor(ex2, off, 64);
        ex3 += __shfl_xor(ex3, off, 64);
    }
    __shared__ float sh[4][4];
    int w = threadIdx.x >> 6;
    if ((threadIdx.x & 63) == 0) {
        sh[w][0] = ex0; sh[w][1] = ex1; sh[w][2] = ex2; sh[w][3] = ex3;
    }
    __syncthreads();
    if (threadIdx.x < 4)
        atomicAdd(&sumexp[threadIdx.x],
                  sh[0][threadIdx.x] + sh[1][threadIdx.x] + sh[2][threadIdx.x] + sh[3][threadIdx.x]);
}

// ---------------- pass 2b (e-order, sequential writes): av[e] = baew*adj ----
__global__ void edge_pass2b(const float4* __restrict__ viewsE, const float* __restrict__ preE,
                            const float* __restrict__ fw, const float* __restrict__ fb,
                            const float* __restrict__ adj, const float* __restrict__ sumexp,
                            float* __restrict__ av, float* __restrict__ neglog, int E) {
    int e = blockIdx.x * blockDim.x + threadIdx.x;
    float nl = 0.f;
    if (e < E) {
        float s0 = sumexp[0], s1 = sumexp[1], s2 = sumexp[2], s3 = sumexp[3];
        float4 v = viewsE[e];
        float fwe = fw[e], fbe = fb[e];
        float w0 = __expf(tanhf(fmaf(fwe, v.x, fbe))) / s0;
        float w1 = __expf(tanhf(fmaf(fwe, v.y, fbe))) / s1;
        float w2 = __expf(tanhf(fmaf(fwe, v.z, fbe))) / s2;
        float w3 = __expf(tanhf(fmaf(fwe, v.w, fbe))) / s3;
        float agw = w0 * v.x + w1 * v.y + w2 * v.z + w3 * v.w;
        float sv = v.x + v.y + v.z + v.w;
        float Ag = (sv - 3.f * agw) * 0.2f;            // (sum(views)-3*Ag)/5
        float bw = preE[e] * Ag;
        av[e] = bw * adj[e];
        nl = -logf(bw);
    }
#pragma unroll
    for (int off = 32; off; off >>= 1) nl += __shfl_xor(nl, off, 64);
    __shared__ float sh4[4];
    if ((threadIdx.x & 63) == 0) sh4[threadIdx.x >> 6] = nl;
    __syncthreads();
    if (threadIdx.x == 0) atomicAdd(neglog, sh4[0] + sh4[1] + sh4[2] + sh4[3]);
}

// ---------------- gather+cvt batch rows, both sides ----------------
__global__ void gather_cvt_both(const float* __restrict__ Zu, const int* __restrict__ uids,
                                unsigned short* __restrict__ Gu,
                                const float* __restrict__ Zi, const int* __restrict__ iids,
                                unsigned short* __restrict__ Gi) {
    int t = blockIdx.x * blockDim.x + threadIdx.x;
    if (t < Bc * 64) {
        Gu[t] = f2bf(Zu[(size_t)uids[t >> 6] * 64 + (t & 63)]);
    } else {
        t -= Bc * 64;
        if (t < Bc * 64) Gi[t] = f2bf(Zi[(size_t)iids[t >> 6] * 64 + (t & 63)]);
    }
}

// ---------------- contrastive LSE via MFMA (core + fused launch) ----------------
__device__ __forceinline__ void lse_core(const unsigned short* __restrict__ Gbf,
                                         const unsigned short* __restrict__ Ebf,
                                         float* __restrict__ sums, int N, int tilesPerChunk,
                                         int wid, int lane) {
    int bgroup = wid & 15;       // 16 groups x 64 b
    int chunk = wid >> 4;
    int ntiles = N >> 4;
    int t0 = chunk * tilesPerChunk;
    if (t0 >= ntiles) return;
    int t1 = t0 + tilesPerChunk; if (t1 > ntiles) t1 = ntiles;
    int m = lane & 15, quad = lane >> 4;

    short8 a0[4], a1[4];
#pragma unroll
    for (int t = 0; t < 4; ++t) {
        const short8* ap = (const short8*)(Gbf + ((size_t)(bgroup * 64 + t * 16 + m)) * 64 + quad * 8);
        a0[t] = ap[0];
        a1[t] = ap[4];
    }
    floatx4 rs[4];
#pragma unroll
    for (int t = 0; t < 4; ++t) rs[t] = (floatx4){0.f, 0.f, 0.f, 0.f};

    for (int jt = t0; jt < t1; ++jt) {
        const short8* bp = (const short8*)(Ebf + ((size_t)(jt * 16 + m)) * 64 + quad * 8);
        short8 bf0 = bp[0], bf1 = bp[4];
#pragma unroll
        for (int t = 0; t < 4; ++t) {
            floatx4 c = (floatx4){0.f, 0.f, 0.f, 0.f};
            c = __builtin_amdgcn_mfma_f32_16x16x32_bf16(a0[t], bf0, c, 0, 0, 0);
            c = __builtin_amdgcn_mfma_f32_16x16x32_bf16(a1[t], bf1, c, 0, 0, 0);
#pragma unroll
            for (int r = 0; r < 4; ++r) rs[t][r] += __expf(c[r] * 5.f);
        }
    }
#pragma unroll
    for (int t = 0; t < 4; ++t) {
#pragma unroll
        for (int r = 0; r < 4; ++r) {
            float v = rs[t][r];
            v += __shfl_xor(v, 1, 64);
            v += __shfl_xor(v, 2, 64);
            v += __shfl_xor(v, 4, 64);
            v += __shfl_xor(v, 8, 64);
            if (m == 0) atomicAdd(&sums[bgroup * 64 + t * 16 + quad * 4 + r], v);
        }
    }
}

__global__ void lse_both(const unsigned short* __restrict__ Gu, const unsigned short* __restrict__ Su,
                         float* __restrict__ sums_u,
                         const unsigned short* __restrict__ Gi, const unsigned short* __restrict__ Si,
                         float* __restrict__ sums_i) {
    int lane = threadIdx.x & 63;
    int w4 = threadIdx.x >> 6;
    if ((int)blockIdx.x < 640) {
        lse_core(Gu, Su, sums_u, NUc, 40, blockIdx.x * 4 + w4, lane);
    } else {
        lse_core(Gi, Si, sums_i, NIc, 40, (blockIdx.x - 640) * 4 + w4, lane);
    }
}

// ---------------- batch partials: wave per b, coalesced row loads ----------------
__global__ void batch_partial(const float* __restrict__ Su, const float* __restrict__ Si,
                              const float* __restrict__ Zu, const float* __restrict__ Zi,
                              const int* __restrict__ uids, const int* __restrict__ iids,
                              const int* __restrict__ pids, const int* __restrict__ nids,
                              float* __restrict__ pos_b, float* __restrict__ bpr_b) {
    int b = blockIdx.x * (blockDim.x >> 6) + (threadIdx.x >> 6);
    if (b >= Bc) return;
    int lane = threadIdx.x & 63;
    int u = uids[b], ii = iids[b], p = pids[b], n = nids[b];
    float zu = Zu[(size_t)u * 64 + lane],  su = Su[(size_t)u * 64 + lane];
    float zi = Zi[(size_t)ii * 64 + lane], si = Si[(size_t)ii * 64 + lane];
    float pe = Si[(size_t)p * 64 + lane],  ne = Si[(size_t)n * 64 + lane];
    float du = zu * su, di = zi * si, dp = su * pe, dn = su * ne;
#pragma unroll
    for (int off = 32; off; off >>= 1) {
        du += __shfl_xor(du, off, 64);
        di += __shfl_xor(di, off, 64);
        dp += __shfl_xor(dp, off, 64);
        dn += __shfl_xor(dn, off, 64);
    }
    if (lane == 0) {
        pos_b[b] = fminf(fmaxf(du * 5.f, -5.f), 5.f) + fminf(fmaxf(di * 5.f, -5.f), 5.f);
        bpr_b[b] = log1pf(__expf(-(dp - dn)));         // -log(sigmoid(diff))
    }
}

// ---------------- all 12 L2-reg sums in one kernel ----------------
__global__ void sumsq_all(const float* __restrict__ p0, const float* __restrict__ p1,
                          const float* __restrict__ p2, const float* __restrict__ p3,
                          const float* __restrict__ p4, const float* __restrict__ p5,
                          const float* __restrict__ p6, const float* __restrict__ p7,
                          const float* __restrict__ p8, const float* __restrict__ p9,
                          const float* __restrict__ p10, const float* __restrict__ p11,
                          float* __restrict__ acc) {
    const int TOT = 6400000 + 3200000 + 3 * 800000 + 3 * 4096 + 128 + 64 + 64 + 1;
    float s = 0.f;
    for (int t = blockIdx.x * blockDim.x + threadIdx.x; t < TOT; t += gridDim.x * blockDim.x) {
        int i = t;
        const float* P;
        if (i < 6400000) P = p0;
        else if ((i -= 6400000) < 3200000) P = p1;
        else if ((i -= 3200000) < 800000) P = p2;
        else if ((i -= 800000) < 800000) P = p3;
        else if ((i -= 800000) < 800000) P = p4;
        else if ((i -= 800000) < 4096) P = p5;
        else if ((i -= 4096) < 4096) P = p6;
        else if ((i -= 4096) < 4096) P = p7;
        else if ((i -= 4096) < 128) P = p8;
        else if ((i -= 128) < 64) P = p9;
        else if ((i -= 64) < 64) P = p10;
        else { i -= 64; P = p11; }
        float v = P[i];
        s = fmaf(v, v, s);
    }
#pragma unroll
    for (int off = 32; off; off >>= 1) s += __shfl_xor(s, off, 64);
    __shared__ float sh[4];
    if ((threadIdx.x & 63) == 0) sh[threadIdx.x >> 6] = s;
    __syncthreads();
    if (threadIdx.x == 0) atomicAdd(acc, sh[0] + sh[1] + sh[2] + sh[3]);
}

// ---------------- final combine (tiny) ----------------
__global__ void finalize_kernel(const float* __restrict__ sumexp_u, const float* __restrict__ sumexp_i,
                                const float* __restrict__ pos_b, const float* __restrict__ bpr_b,
                                const float* __restrict__ neglog, const float* __restrict__ regsum,
                                float* __restrict__ out) {
    int b = threadIdx.x;  // 1024
    float lse = logf(sumexp_u[b] + 1e-8f) + logf(sumexp_i[b] + 1e-8f);
    float pos = pos_b[b];
    float bpr = bpr_b[b];
#pragma unroll
    for (int off = 32; off; off >>= 1) {
        lse += __shfl_xor(lse, off, 64);
        pos += __shfl_xor(pos, off, 64);
        bpr += __shfl_xor(bpr, off, 64);
    }
    __shared__ float sl[16], sp[16], sb[16];
    int w = b >> 6;
    if ((b & 63) == 0) { sl[w] = lse; sp[w] = pos; sb[w] = bpr; }
    __syncthreads();
    if (b == 0) {
        float L = 0.f, P = 0.f, Bz = 0.f;
        for (int i = 0; i < 16; ++i) { L += sl[i]; P += sp[i]; Bz += sb[i]; }
        float neg_sc = L * (1.f / Bc);
        float pos_sc = P * (1.f / Bc);
        float loss_cl = neg_sc - pos_sc;
        float l1cl = 0.2f * loss_cl;
        float loss_bpr = Bz * (1.f / Bc);
        float loss_pr = 0.01f * (neglog[0] * (1.f / Ec));
        float loss_reg = 1e-5f * regsum[0];
        out[0] = loss_bpr + l1cl + loss_pr + loss_reg;
        out[1] = loss_bpr;
        out[2] = l1cl;
        out[3] = loss_pr;
    }
}

extern "C" void kernel_launch(void* const* d_in, const int* in_sizes, int n_in,
                              void* d_out, int out_size, void* d_ws, size_t ws_size,
                              hipStream_t stream) {
    const float* Eu0    = (const float*)d_in[0];
    const float* Ei0    = (const float*)d_in[1];
    const float* fuse_w = (const float*)d_in[2];
    const float* fuse_b = (const float*)d_in[3];
    const float* W1u    = (const float*)d_in[4];
    const float* W1i    = (const float*)d_in[5];
    const float* b1     = (const float*)d_in[6];
    const float* W2     = (const float*)d_in[7];
    const float* b2     = (const float*)d_in[8];
    const float* att    = (const float*)d_in[9];
    const float* wv     = (const float*)d_in[10];
    const float* Wg     = (const float*)d_in[11];
    const float* adj    = (const float*)d_in[12];
    const float* dmain  = (const float*)d_in[13];
    const float* daug   = (const float*)d_in[14];
    const int*   esrc   = (const int*)d_in[15];
    const int*   edst   = (const int*)d_in[16];
    const int*   uids   = (const int*)d_in[17];
    const int*   iids   = (const int*)d_in[18];
    const int*   pids   = (const int*)d_in[19];
    const int*   nids   = (const int*)d_in[20];
    float* out = (float*)d_out;

    // ---- workspace layout (~224 MB; proven safe) ----
    char* base = (char*)d_ws;
    size_t off = 0;
    auto alloc = [&](size_t bytes) -> char* {
        char* pp = base + off;
        off = (off + bytes + 255) & ~(size_t)255;
        return pp;
    };
    float* Su   = (float*)alloc((size_t)NUc * 64 * 4);
    float* Si   = (float*)alloc((size_t)NIc * 64 * 4);
    // blkZ (38.4 MB): PU [prep..pass1] -> viewsE/preE [pass2a..pass2b] -> Zu/Zi [prop2..finalize]
    char* blkZ = alloc((size_t)NUc * 64 * 4 + (size_t)NIc * 64 * 4);
    unsigned short* PU = (unsigned short*)blkZ;
    float4* viewsE = (float4*)blkZ;
    float* preE   = (float*)(blkZ + (size_t)Ec * 16);
    float* Zu = (float*)blkZ;
    float* Zi = (float*)(blkZ + (size_t)NUc * 64 * 4);
    float4* vp4 = (float4*)alloc((size_t)Ec * 16);
    unsigned short* Eu0bf = (unsigned short*)alloc((size_t)NUc * 64 * 2);
    unsigned short* Ei0bf = (unsigned short*)alloc((size_t)NIc * 64 * 2);
    unsigned short* Subf  = (unsigned short*)alloc((size_t)NUc * 64 * 2);
    unsigned short* Sibf  = (unsigned short*)alloc((size_t)NIc * 64 * 2);
    unsigned short* Bubf  = (unsigned short*)alloc((size_t)NUc * 64 * 2);
    unsigned short* Bibf  = (unsigned short*)alloc((size_t)NIc * 64 * 2);
    unsigned short* hubf  = (unsigned short*)alloc((size_t)NUc * 64 * 2);
    unsigned short* hibf  = (unsigned short*)alloc((size_t)NIc * 64 * 2);
    // blkA (19.2 MB): adjP [build..GCN spmm] -> PI [prep..pass1] -> wA [build_w_aug..prop2]
    char* blkA = alloc((size_t)Ec * 4 * 6);
    float* adjPu = (float*)blkA;
    float* adjPi = (float*)(blkA + (size_t)Ec * 4);
    float* wAu0  = (float*)(blkA + (size_t)Ec * 8);
    float* wAu1  = (float*)(blkA + (size_t)Ec * 12);
    float* wAi0  = (float*)(blkA + (size_t)Ec * 16);
    float* wAi1  = (float*)(blkA + (size_t)Ec * 20);
    unsigned short* PI = (unsigned short*)blkA;
    float* wMu0  = (float*)alloc((size_t)Ec * 4);
    float* wMu1  = (float*)alloc((size_t)Ec * 4);
    float* wMi0  = (float*)alloc((size_t)Ec * 4);
    float* wMi1  = (float*)alloc((size_t)Ec * 4);
    float* av    = (float*)alloc((size_t)Ec * 4);
    float* auv  = (float*)alloc((size_t)NUc * 4);
    float* aiv  = (float*)alloc((size_t)NIc * 4);
    int* rowu  = (int*)alloc((size_t)Ec * 4);
    unsigned short* Gubf = (unsigned short*)alloc((size_t)Bc * 64 * 2);
    unsigned short* Gibf = (unsigned short*)alloc((size_t)Bc * 64 * 2);
    // contiguous scalar-accumulator block (one memset)
    float* scal = (float*)alloc((4 + 1 + 1 + 2 + Bc + Bc) * 4);
    float* sumexp4 = scal;            // 4
    float* neglog  = scal + 4;        // 1
    float* regsum  = scal + 5;        // 1 (+2 pad)
    float* sumexp_u = scal + 8;       // 1024
    float* sumexp_i = scal + 8 + Bc;  // 1024
    float* pos_b = (float*)alloc((size_t)Bc * 4);
    float* bpr_b = (float*)alloc((size_t)Bc * 4);
    int* rpu   = (int*)alloc((size_t)(NUc + 1) * 4);
    int* rpi   = (int*)alloc((size_t)(NIc + 1) * 4);
    int* colu  = (int*)alloc((size_t)Ec * 4);
    int* coli  = (int*)alloc((size_t)Ec * 4);
    int* posu  = (int*)alloc((size_t)Ec * 4);
    int* permu = (int*)alloc((size_t)Ec * 4);
    int* permi = (int*)alloc((size_t)Ec * 4);
    int* cntAll  = (int*)alloc((size_t)(NUc + NIc) * 4);
    int* scanAll = (int*)alloc((size_t)(NUc + NIc) * 4);
    int* curu  = (int*)alloc((size_t)NUc * 4);
    int* curi  = (int*)alloc((size_t)NIc * 4);
    int* bsum  = (int*)alloc(256 * 4);

    dim3 b256(256);
    const int NALL = NUc + NIc;
    const int nbAll = (NALL + 1023) / 1024;   // 147
    const dim3 gE((Ec + 255) / 256);
    const dim3 g2E((2 * Ec + 255) / 256);
    const int blocksU = (NUc + 3) / 4, blocksI = (NIc + 3) / 4;   // 25000 / 12500
    const dim3 gUI(blocksU + blocksI);

    // ---- zero accumulators + counts (2 memsets total) ----
    hipMemsetAsync(cntAll, 0, (size_t)NALL * 4, stream);
    hipMemsetAsync(scal, 0, (4 + 1 + 1 + 2 + Bc + Bc) * 4, stream);

    // ---- CSR build (fused) ----
    hist_both<<<gE, b256, 0, stream>>>(esrc, edst, cntAll, Ec);
    scan_block<<<dim3(nbAll), dim3(1024), 0, stream>>>(cntAll, scanAll, bsum, NALL);
    scan_bsums<<<dim3(1), dim3(256), 0, stream>>>(bsum, nbAll);
    scan_add_cur<<<dim3((NALL + 255) / 256), b256, 0, stream>>>(scanAll, bsum, cntAll,
                                                               rpu, rpi, curu, curi);
    fill_both<<<g2E, b256, 0, stream>>>(esrc, edst, curu, curi, colu, posu, permu, coli, permi, Ec);
    build_rowu<<<dim3((NUc + 255) / 256), b256, 0, stream>>>(rpu, rowu, NUc);

    // ---- main weights + adjacency in CSR order (one kernel) ----
    build_w_main_both<<<g2E, b256, 0, stream>>>(permu, permi, adj, dmain,
                                                wMu0, wMu1, adjPu, wMi0, wMi1, adjPi);

    // ---- bf16 base embeddings (one kernel) ----
    cvt_both<<<dim3(((NUc + NIc) * 16 + 255) / 256), b256, 0, stream>>>(
        (const float4*)Eu0, (ushort4*)Eu0bf, NUc * 16,
        (const float4*)Ei0, (ushort4*)Ei0bf, NIc * 16);

    // ---- propagate 1 (main graph), fused u+i per layer ----
    spmm_bf2<<<gUI, b256, 0, stream>>>(blocksU,
        rpu, colu, wMu0, Ei0bf, Su, Eu0, Bubf, nullptr, NUc,
        rpi, coli, wMi0, Eu0bf, Si, Ei0, Bibf, nullptr, NIc);
    spmm_bf2<<<gUI, b256, 0, stream>>>(blocksU,
        rpu, colu, wMu1, Bibf, Su, nullptr, nullptr, Subf, NUc,     // fused Su->bf16
        rpi, coli, wMi1, Bubf, Si, nullptr, nullptr, Sibf, NIc);    // fused Si->bf16

    // ---- GCN view: h_u = A@Si ; h_i = A.T@Su (fused) ----
    spmm_bf2<<<gUI, b256, 0, stream>>>(blocksU,
        rpu, colu, adjPu, Sibf, nullptr, nullptr, hubf, nullptr, NUc,
        rpi, coli, adjPi, Subf, nullptr, nullptr, hibf, nullptr, NIc);

    // ---- node-feature prep via MFMA (one kernel) ----
    {
        const int tBU = (NUc / 16 + 3) / 4;   // 1563
        const int tBI = (NIc / 16 + 3) / 4;   // 782
        prep_both<<<dim3(tBU + tBI), b256, 0, stream>>>(
            Eu0bf, hubf, Subf, Ei0bf, hibf, Sibf,
            W1u, Wg, W1i, att, PU, PI, auv, aiv, tBU);
    }

    // ---- edge pass 1 (CSR-u order, LDS-staged) ----
    edge_pass1<<<dim3(Ec / 128), dim3(128), 0, stream>>>(
        rowu, colu, PU, PI, b1, W2, b2, auv, aiv, vp4, Ec);

    // ---- pass 2a: views (e-order) + softmax-exp sums (overwrites PU alias) ----
    edge_pass2a<<<gE, b256, 0, stream>>>(vp4, posu, fuse_w, fuse_b, wv,
                                         viewsE, preE, sumexp4, Ec);

    // ---- pass 2b: av[e] sequential + -log(baew) sum ----
    edge_pass2b<<<gE, b256, 0, stream>>>(
        viewsE, preE, fuse_w, fuse_b, adj, sumexp4, av, neglog, Ec);

    // ---- aug weights in CSR order (one kernel; overwrites PI alias) ----
    build_w_aug_both<<<g2E, b256, 0, stream>>>(permu, permi, av, daug, wAu0, wAu1, wAi0, wAi1);

    // ---- propagate 2 (augmented graph), fused u+i (overwrites viewsE alias) ----
    spmm_bf2<<<gUI, b256, 0, stream>>>(blocksU,
        rpu, colu, wAu0, Ei0bf, Zu, Eu0, Bubf, nullptr, NUc,
        rpi, coli, wAi0, Eu0bf, Zi, Ei0, Bibf, nullptr, NIc);
    spmm_bf2<<<gUI, b256, 0, stream>>>(blocksU,
        rpu, colu, wAu1, Bibf, Zu, nullptr, nullptr, nullptr, NUc,
        rpi, coli, wAi1, Bubf, Zi, nullptr, nullptr, nullptr, NIc);

    // ---- contrastive ----
    gather_cvt_both<<<dim3((2 * Bc * 64 + 255) / 256), b256, 0, stream>>>(
        Zu, uids, Gubf, Zi, iids, Gibf);
    lse_both<<<dim3(960), b256, 0, stream>>>(Gubf, Subf, sumexp_u, Gibf, Sibf, sumexp_i);

    // ---- batch partials ----
    batch_partial<<<dim3(Bc / 4), b256, 0, stream>>>(Su, Si, Zu, Zi, uids, iids, pids, nids,
                                                     pos_b, bpr_b);

    // ---- regularization (one kernel) ----
    sumsq_all<<<dim3(4096), b256, 0, stream>>>(Eu0, Ei0, fuse_w, fuse_b, wv,
                                               W1u, W1i, Wg, att, b1, W2, b2, regsum);

    // ---- finalize ----
    finalize_kernel<<<dim3(1), dim3(1024), 0, stream>>>(
        sumexp_u, sumexp_i, pos_b, bpr_b, neglog, regsum, out);
}